// Round 12
// baseline (160.180 us; speedup 1.0000x reference)
//
#include <hip/hip_runtime.h>
#include <hip/hip_bf16.h>
#include <hip/hip_fp16.h>
#include <hip/hip_cooperative_groups.h>

namespace cg = cooperative_groups;

#define BATCH 16384
#define HIST  50
#define ITEM_ROWS 100001
#define EMB   64
#define N8    (ITEM_ROWS * EMB / 8)   // 800008
#define GRID  1024                     // 4 blocks/CU at 256 CUs -> co-resident

typedef float v2f __attribute__((ext_vector_type(2)));

// DPP row_ror (16-lane row scope) reduction — pure VALU, no LDS pipe.
template<int CTRL>
__device__ __forceinline__ float dpp_mov(float x) {
    return __builtin_bit_cast(float,
        __builtin_amdgcn_update_dpp(0, __builtin_bit_cast(int, x),
                                    CTRL, 0xF, 0xF, true));
}
__device__ __forceinline__ float red16_add(float x) {
    x += dpp_mov<0x128>(x);   // row_ror:8
    x += dpp_mov<0x124>(x);   // row_ror:4
    x += dpp_mov<0x122>(x);   // row_ror:2
    x += dpp_mov<0x121>(x);   // row_ror:1
    return x;
}
__device__ __forceinline__ float dot4(float4 a, float4 b) {
    return a.x*b.x + a.y*b.y + a.z*b.z + a.w*b.w;
}

// R9's proven per-element body: group-of-16 layout, fp8 rows, 13 lines in
// flight, index distribution via shuffle, DPP reductions.
__device__ __forceinline__ void process_one(
    int b, int lane, int lane16, int g, int xi,
    const unsigned* __restrict__ item8,
    const float4* __restrict__ item4, const float4* __restrict__ user4,
    const int* __restrict__ u, const int* __restrict__ y,
    float* __restrict__ out)
{
    const int yi = y[b];                                // wave-uniform scalars
    const int ui = u[b];
    const float4 y4 = item4[(size_t)yi * 16 + lane16];  // exact fp32
    const float4 u4 = user4[(size_t)ui * 16 + lane16];  // exact fp32

    const int start = (g < 2) ? g * 13 : 26 + (g - 2) * 12;
    const int count = (g < 2) ? 13 : 12;

    int idxs[13];
    #pragma unroll
    for (int k = 0; k < 13; ++k) {
        const int s = __shfl(xi, start + k, 64);
        idxs[k] = (k < count) ? s : 0;                  // row 0 = zeros
    }

    unsigned q[13];
    #pragma unroll
    for (int k = 0; k < 13; ++k)
        q[k] = item8[(size_t)idxs[k] * 16 + lane16];    // 1 x 64 B line/row

    const float uy = red16_add(dot4(u4, y4));           // overlaps gather

    float wv = -1e30f;
    #pragma unroll
    for (int k = 0; k < 13; ++k) {
        const v2f lo = __builtin_amdgcn_cvt_pk_f32_fp8((int)q[k], false);
        const v2f hi = __builtin_amdgcn_cvt_pk_f32_fp8((int)q[k], true);
        const float w = red16_add(lo.x*y4.x + lo.y*y4.y + hi.x*y4.z + hi.y*y4.w);
        if (k < count && lane16 == k) wv = w;
    }

    float m = wv;
    #pragma unroll
    for (int d = 1; d < 16; d <<= 1) m = fmaxf(m, __shfl_xor(m, d, 16));
    m = fmaxf(m, __shfl_xor(m, 16, 64));
    m = fmaxf(m, __shfl_xor(m, 32, 64));

    const float e = __expf(wv - m);                     // pads: exp(-huge)=0
    float s = red16_add(e);
    float t = red16_add(e * wv);
    s += __shfl_xor(s, 16, 64);  s += __shfl_xor(s, 32, 64);
    t += __shfl_xor(t, 16, 64);  t += __shfl_xor(t, 32, 64);

    if (lane == 0) {
        const float logit = t / s + uy;
        out[b] = 1.0f / (1.0f + __expf(-logit));
    }
}

// ---- fused cooperative kernel: convert fp32->fp8, grid sync, gather ----
// out[b] = sigmoid( sum_l z_l*w_l + u_e.y_e ), z = softmax(w)  [BETA=ALPHA=1]
__global__ __launch_bounds__(256, 4) void RUM_72980084294375_kernel(
    const int* __restrict__ u, const int* __restrict__ X, const int* __restrict__ y,
    const float* __restrict__ item_emb, const float* __restrict__ user_emb,
    unsigned* __restrict__ ws8, float* __restrict__ out)
{
    const int tid = threadIdx.x;

    // ---- phase 1: fp32 item table -> fp8 e4m3 table (grid-stride) ----
    {
        const float4* in4 = reinterpret_cast<const float4*>(item_emb);
        uint2* o2 = reinterpret_cast<uint2*>(ws8);
        for (int i = blockIdx.x * 256 + tid; i < N8; i += GRID * 256) {
            const float4 x0 = in4[2 * i];
            const float4 x1 = in4[2 * i + 1];
            int p0 = 0, p1 = 0;
            p0 = __builtin_amdgcn_cvt_pk_fp8_f32(x0.x, x0.y, p0, false);
            p0 = __builtin_amdgcn_cvt_pk_fp8_f32(x0.z, x0.w, p0, true);
            p1 = __builtin_amdgcn_cvt_pk_fp8_f32(x1.x, x1.y, p1, false);
            p1 = __builtin_amdgcn_cvt_pk_fp8_f32(x1.z, x1.w, p1, true);
            o2[i] = make_uint2((unsigned)p0, (unsigned)p1);
        }
    }

    // ---- phase 2 front-end: X-index loads (independent of ws8) issued
    // before the grid sync so their latency hides under the convert tail.
    const int wave   = tid >> 6;
    const int lane   = tid & 63;
    const int lane16 = lane & 15;
    const int g      = lane >> 4;
    const int wid    = blockIdx.x * 4 + wave;           // 0..4095
    const int bbase  = __builtin_amdgcn_readfirstlane(wid * 4);

    int xi0 = 0, xi1 = 0, xi2 = 0, xi3 = 0;
    if (lane < HIST) {
        xi0 = X[(bbase + 0) * HIST + lane];             // coalesced 200 B each
        xi1 = X[(bbase + 1) * HIST + lane];
        xi2 = X[(bbase + 2) * HIST + lane];
        xi3 = X[(bbase + 3) * HIST + lane];
    }

    cg::this_grid().sync();

    // ---- phase 2: 4 batch elements per wave ----
    const unsigned* item8 = ws8;
    const float4* item4 = reinterpret_cast<const float4*>(item_emb);
    const float4* user4 = reinterpret_cast<const float4*>(user_emb);

    process_one(bbase + 0, lane, lane16, g, xi0, item8, item4, user4, u, y, out);
    process_one(bbase + 1, lane, lane16, g, xi1, item8, item4, user4, u, y, out);
    process_one(bbase + 2, lane, lane16, g, xi2, item8, item4, user4, u, y, out);
    process_one(bbase + 3, lane, lane16, g, xi3, item8, item4, user4, u, y, out);
}

// ---- fp32 fallback if ws is too small (R7 structure, two-kernel-free) ----
__global__ __launch_bounds__(256, 4) void RUM_72980084294375_f32_kernel(
    const int* __restrict__ u, const int* __restrict__ X, const int* __restrict__ y,
    const float* __restrict__ item_emb, const float* __restrict__ user_emb,
    float* __restrict__ out)
{
    const int tid    = threadIdx.x;
    const int wave   = tid >> 6;
    const int lane   = tid & 63;
    const int lane16 = lane & 15;
    const int g      = lane >> 4;
    const int b      = __builtin_amdgcn_readfirstlane(blockIdx.x * 4 + wave);

    int xi = 0;
    if (lane < HIST) xi = X[b * HIST + lane];

    const float4* item4 = reinterpret_cast<const float4*>(item_emb);
    const float4* user4 = reinterpret_cast<const float4*>(user_emb);
    const int yi = y[b];
    const int ui = u[b];
    const float4 y4 = item4[(size_t)yi * 16 + lane16];
    const float4 u4 = user4[(size_t)ui * 16 + lane16];

    const float uy = red16_add(dot4(u4, y4));

    const int start = (g < 2) ? g * 13 : 26 + (g - 2) * 12;
    const int count = (g < 2) ? 13 : 12;

    float wv = -1e30f;
    #pragma unroll
    for (int k = 0; k < 13; ++k) {
        const int s = __shfl(xi, start + k, 64);
        const int idx = (k < count) ? s : 0;
        const float4 x4 = item4[(size_t)idx * 16 + lane16];
        const float w = red16_add(dot4(x4, y4));
        if (k < count && lane16 == k) wv = w;
    }

    float m = wv;
    #pragma unroll
    for (int d = 1; d < 16; d <<= 1) m = fmaxf(m, __shfl_xor(m, d, 16));
    m = fmaxf(m, __shfl_xor(m, 16, 64));
    m = fmaxf(m, __shfl_xor(m, 32, 64));

    const float e = __expf(wv - m);
    float s = red16_add(e);
    float t = red16_add(e * wv);
    s += __shfl_xor(s, 16, 64);  s += __shfl_xor(s, 32, 64);
    t += __shfl_xor(t, 16, 64);  t += __shfl_xor(t, 32, 64);

    if (lane == 0) {
        const float logit = t / s + uy;
        out[b] = 1.0f / (1.0f + __expf(-logit));
    }
}

extern "C" void kernel_launch(void* const* d_in, const int* in_sizes, int n_in,
                              void* d_out, int out_size, void* d_ws, size_t ws_size,
                              hipStream_t stream) {
    const int*   u        = (const int*)d_in[0];
    const int*   X        = (const int*)d_in[1];
    const int*   y        = (const int*)d_in[2];
    const float* item_emb = (const float*)d_in[3];
    const float* user_emb = (const float*)d_in[4];
    float*       out      = (float*)d_out;

    const size_t need = (size_t)ITEM_ROWS * EMB;     // 6.4 MB fp8 table

    if (ws_size >= need) {
        unsigned* ws8 = (unsigned*)d_ws;
        void* args[] = { (void*)&u, (void*)&X, (void*)&y,
                         (void*)&item_emb, (void*)&user_emb,
                         (void*)&ws8, (void*)&out };
        hipLaunchCooperativeKernel((const void*)RUM_72980084294375_kernel,
                                   dim3(GRID), dim3(256), args, 0, stream);
    } else {
        RUM_72980084294375_f32_kernel<<<BATCH / 4, 256, 0, stream>>>(
            u, X, y, item_emb, user_emb, out);
    }
}

// Round 13
// 24.069 us; speedup vs baseline: 6.6549x; 6.6549x over previous
//
#include <hip/hip_runtime.h>
#include <hip/hip_bf16.h>
#include <hip/hip_fp16.h>

#define BATCH 16384
#define HIST  50
#define ITEM_ROWS 100001
#define EMB   64

typedef float v2f __attribute__((ext_vector_type(2)));

// DPP row_ror (16-lane row scope) reduction — pure VALU, no LDS pipe.
template<int CTRL>
__device__ __forceinline__ float dpp_mov(float x) {
    return __builtin_bit_cast(float,
        __builtin_amdgcn_update_dpp(0, __builtin_bit_cast(int, x),
                                    CTRL, 0xF, 0xF, true));
}
__device__ __forceinline__ float red16_add(float x) {
    x += dpp_mov<0x128>(x);   // row_ror:8
    x += dpp_mov<0x124>(x);   // row_ror:4
    x += dpp_mov<0x122>(x);   // row_ror:2
    x += dpp_mov<0x121>(x);   // row_ror:1
    return x;
}
__device__ __forceinline__ float dot4(float4 a, float4 b) {
    return a.x*b.x + a.y*b.y + a.z*b.z + a.w*b.w;
}

// ---- kernel 1: fp32 item table -> fp8 e4m3 table in workspace ----
__global__ __launch_bounds__(256) void cvt_fp8_kernel(
    const float4* __restrict__ in4, uint2* __restrict__ out, int n8)
{
    const int i = blockIdx.x * 256 + threadIdx.x;
    if (i >= n8) return;
    const float4 x0 = in4[2 * i];
    const float4 x1 = in4[2 * i + 1];
    int p0 = 0, p1 = 0;
    p0 = __builtin_amdgcn_cvt_pk_fp8_f32(x0.x, x0.y, p0, false);
    p0 = __builtin_amdgcn_cvt_pk_fp8_f32(x0.z, x0.w, p0, true);
    p1 = __builtin_amdgcn_cvt_pk_fp8_f32(x1.x, x1.y, p1, false);
    p1 = __builtin_amdgcn_cvt_pk_fp8_f32(x1.z, x1.w, p1, true);
    out[i] = make_uint2((unsigned)p0, (unsigned)p1);
}

// ---- kernel 2: R9 structure at DOUBLE occupancy (8 waves/SIMD, <=64 VGPR).
// One wave per batch element; 4 groups of 16 lanes; group g handles
// 13/13/12/12 rows; indices in lane registers, shuffled directly into the
// gather loop (no idxs[] array, no LDS, no barrier).
// x-rows: fp8 (64 B/row = 1 line). y/u rows: original fp32 (coalesced).
// out[b] = sigmoid( sum_l z_l*w_l + u_e.y_e ), z = softmax(w)  [BETA=ALPHA=1]
__global__ __launch_bounds__(256, 8) void RUM_72980084294375_kernel(
    const int* __restrict__ u, const int* __restrict__ X, const int* __restrict__ y,
    const unsigned* __restrict__ item8, const float* __restrict__ item_emb,
    const float* __restrict__ user_emb, float* __restrict__ out)
{
    const int tid    = threadIdx.x;
    const int wave   = tid >> 6;
    const int lane   = tid & 63;
    const int lane16 = lane & 15;
    const int g      = lane >> 4;
    const int b      = __builtin_amdgcn_readfirstlane(blockIdx.x * 4 + wave);

    // issue ALL independent loads up front: indices (lane-owned), y-row, u-row
    int xi = 0;
    if (lane < HIST) xi = X[b * HIST + lane];           // coalesced 200 B

    const float4* item4 = reinterpret_cast<const float4*>(item_emb);
    const float4* user4 = reinterpret_cast<const float4*>(user_emb);
    const int yi = y[b];                                // wave-uniform scalars
    const int ui = u[b];
    const float4 y4 = item4[(size_t)yi * 16 + lane16];  // exact fp32
    const float4 u4 = user4[(size_t)ui * 16 + lane16];  // exact fp32

    const int start = (g < 2) ? g * 13 : 26 + (g - 2) * 12;
    const int count = (g < 2) ? 13 : 12;

    // issue all 13 row-gathers back-to-back; shuffle consumed in-loop
    unsigned q[13];
    #pragma unroll
    for (int k = 0; k < 13; ++k) {
        const int s = __shfl(xi, start + k, 64);
        const int idx = (k < count) ? s : 0;            // row 0 = zeros
        q[k] = item8[(size_t)idx * 16 + lane16];        // 1 x 64 B line/row
    }

    const float uy = red16_add(dot4(u4, y4));           // overlaps gather

    // decode + dot + 16-lane reduce
    float wv = -1e30f;
    #pragma unroll
    for (int k = 0; k < 13; ++k) {
        const v2f lo = __builtin_amdgcn_cvt_pk_f32_fp8((int)q[k], false);
        const v2f hi = __builtin_amdgcn_cvt_pk_f32_fp8((int)q[k], true);
        const float w = red16_add(lo.x*y4.x + lo.y*y4.y + hi.x*y4.z + hi.y*y4.w);
        if (k < count && lane16 == k) wv = w;
    }

    // softmax-weighted mean across all 50 (16-lane reduce + cross-group)
    float m = wv;
    #pragma unroll
    for (int d = 1; d < 16; d <<= 1) m = fmaxf(m, __shfl_xor(m, d, 16));
    m = fmaxf(m, __shfl_xor(m, 16, 64));
    m = fmaxf(m, __shfl_xor(m, 32, 64));

    const float e = __expf(wv - m);                     // pads: exp(-huge)=0
    float s = red16_add(e);
    float t = red16_add(e * wv);
    s += __shfl_xor(s, 16, 64);  s += __shfl_xor(s, 32, 64);
    t += __shfl_xor(t, 16, 64);  t += __shfl_xor(t, 32, 64);

    if (lane == 0) {
        const float logit = t / s + uy;
        out[b] = 1.0f / (1.0f + __expf(-logit));
    }
}

// ---- fp32 fallback if ws is too small ----
__global__ __launch_bounds__(256, 4) void RUM_72980084294375_f32_kernel(
    const int* __restrict__ u, const int* __restrict__ X, const int* __restrict__ y,
    const float* __restrict__ item_emb, const float* __restrict__ user_emb,
    float* __restrict__ out)
{
    const int tid    = threadIdx.x;
    const int wave   = tid >> 6;
    const int lane   = tid & 63;
    const int lane16 = lane & 15;
    const int g      = lane >> 4;
    const int b      = __builtin_amdgcn_readfirstlane(blockIdx.x * 4 + wave);

    int xi = 0;
    if (lane < HIST) xi = X[b * HIST + lane];

    const float4* item4 = reinterpret_cast<const float4*>(item_emb);
    const float4* user4 = reinterpret_cast<const float4*>(user_emb);
    const int yi = y[b];
    const int ui = u[b];
    const float4 y4 = item4[(size_t)yi * 16 + lane16];
    const float4 u4 = user4[(size_t)ui * 16 + lane16];

    const float uy = red16_add(dot4(u4, y4));

    const int start = (g < 2) ? g * 13 : 26 + (g - 2) * 12;
    const int count = (g < 2) ? 13 : 12;

    float wv = -1e30f;
    #pragma unroll
    for (int k = 0; k < 13; ++k) {
        const int s = __shfl(xi, start + k, 64);
        const int idx = (k < count) ? s : 0;
        const float4 x4 = item4[(size_t)idx * 16 + lane16];
        const float w = red16_add(dot4(x4, y4));
        if (k < count && lane16 == k) wv = w;
    }

    float m = wv;
    #pragma unroll
    for (int d = 1; d < 16; d <<= 1) m = fmaxf(m, __shfl_xor(m, d, 16));
    m = fmaxf(m, __shfl_xor(m, 16, 64));
    m = fmaxf(m, __shfl_xor(m, 32, 64));

    const float e = __expf(wv - m);
    float s = red16_add(e);
    float t = red16_add(e * wv);
    s += __shfl_xor(s, 16, 64);  s += __shfl_xor(s, 32, 64);
    t += __shfl_xor(t, 16, 64);  t += __shfl_xor(t, 32, 64);

    if (lane == 0) {
        const float logit = t / s + uy;
        out[b] = 1.0f / (1.0f + __expf(-logit));
    }
}

extern "C" void kernel_launch(void* const* d_in, const int* in_sizes, int n_in,
                              void* d_out, int out_size, void* d_ws, size_t ws_size,
                              hipStream_t stream) {
    const int*   u        = (const int*)d_in[0];
    const int*   X        = (const int*)d_in[1];
    const int*   y        = (const int*)d_in[2];
    const float* item_emb = (const float*)d_in[3];
    const float* user_emb = (const float*)d_in[4];
    float*       out      = (float*)d_out;

    const size_t need = (size_t)ITEM_ROWS * EMB;     // 6.4 MB fp8 table

    if (ws_size >= need) {
        const int n8 = ITEM_ROWS * EMB / 8;          // 800008 (divides exactly)
        cvt_fp8_kernel<<<(n8 + 255) / 256, 256, 0, stream>>>(
            (const float4*)item_emb, (uint2*)d_ws, n8);
        RUM_72980084294375_kernel<<<BATCH / 4, 256, 0, stream>>>(
            u, X, y, (const unsigned*)d_ws, item_emb, user_emb, out);
    } else {
        RUM_72980084294375_f32_kernel<<<BATCH / 4, 256, 0, stream>>>(
            u, X, y, item_emb, user_emb, out);
    }
}